// Round 2
// baseline (391.734 us; speedup 1.0000x reference)
//
#include <hip/hip_runtime.h>

// DNAMite GAM on MI355X. Round 5: latency hiding. Round 4 was latency-bound
// (319K cyc vs ~100-127K pipe floor): every tile had an exposed pt->emb
// dependent-load chain between barriers, 3 barriers/tile, 3 blocks/CU.
// Now: all bin indices preloaded at block start; sA double-buffered with
// register prefetch of the next tile's embeddings (loads issued before GEMM0,
// f32->f16 convert deferred to store time so the vmcnt wait lands after
// GEMM1); 2 barriers/tile; tile loop fully unrolled (static reg indexing);
// 4 blocks/CU via __launch_bounds__(256,4).

typedef _Float16 f16x8 __attribute__((ext_vector_type(8)));
typedef _Float16 f16x4 __attribute__((ext_vector_type(4)));
typedef float f32x4 __attribute__((ext_vector_type(4)));

constexpr int Bsz = 512;
constexpr int NF  = 64;
constexpr int NE  = 32;
constexpr int NH  = 128;
constexpr int NP  = 2016;
constexpr int NG  = NP + NF;       // 2080 groups = grid
constexpr int BT  = 64;            // batch tile
constexpr int NT  = Bsz / BT;      // 8 tiles
constexpr int NSEG = 8, GSEG = NG / NSEG;  // 260

// ws layout (floats): [NG*Bsz] partials | [NSEG*Bsz] stage2 | pairsT ints
constexpr size_t WS_S2 = (size_t)NG * Bsz;
constexpr size_t WS_PT = WS_S2 + (size_t)NSEG * Bsz;

__device__ __forceinline__ float smoothz(float z) {
  float s = fmaf(-2.0f * z * z, z, fmaf(1.5f, z, 0.5f));
  if (z <= -0.5f) s = 0.0f;
  if (z >=  0.5f) s = 1.0f;
  return s;
}

// [512][4032] -> [4032][512] int transpose, LDS-tiled 32x32.
__global__ void transpose_pairs_kernel(const int* __restrict__ pairs,
                                       int* __restrict__ pt) {
  __shared__ int tile[32][33];
  const int bt = blockIdx.x;
  const int qt = blockIdx.y;
  const int t  = threadIdx.x;
  const int tq = t & 7, tb = t >> 3;
  const int brow  = bt * 32 + tb;
  const int qbase = qt * 32 + tq * 4;
#pragma unroll
  for (int j = 0; j < 4; ++j)
    tile[tb][tq * 4 + j] = pairs[brow * (2 * NP) + qbase + j];
  __syncthreads();
  const int ob = t & 7, oq = t >> 3;
  const int qrow = qt * 32 + oq;
#pragma unroll
  for (int j = 0; j < 4; ++j)
    pt[(size_t)qrow * Bsz + bt * 32 + ob * 4 + j] = tile[ob * 4 + j][oq];
}

// Load one A-fragment of W^T: 8 consecutive k (rows of W) at a fixed column.
__device__ __forceinline__ f16x8 load_col_frag(const float* __restrict__ p) {
  f16x8 f;
#pragma unroll
  for (int j = 0; j < 8; ++j) f[j] = (_Float16)p[(size_t)(j * NH)];
  return f;
}

__global__ __launch_bounds__(256, 4) void fused_groups_kernel(
    const int* __restrict__ mains, const int* __restrict__ pt,
    const float* __restrict__ emb,
    const float* __restrict__ mw0, const float* __restrict__ mw1,
    const float* __restrict__ mw2, const float* __restrict__ mb0,
    const float* __restrict__ mb1, const float* __restrict__ mb2,
    const float* __restrict__ z_main,
    const float* __restrict__ pw0, const float* __restrict__ pw1,
    const float* __restrict__ pw2, const float* __restrict__ pb0,
    const float* __restrict__ pb1, const float* __restrict__ pb2,
    const float* __restrict__ z_pairs,
    const int* __restrict__ pairs_list, const int* __restrict__ foff,
    float* __restrict__ ws) {
  __shared__ _Float16 sA[2][BT * 64];           // double-buffered, 2x8 KB
  __shared__ _Float16 sH[BT * NH];              // 16 KB
  __shared__ __align__(16) float sBias[3 * NH]; // b0 | b1 | w2
  __shared__ float sRed[4 * BT];

  const int t    = threadIdx.x;
  const int wave = t >> 6;
  const int lane = t & 63;
  const int l    = lane & 15;
  const int qd   = lane >> 4;
  const int g    = blockIdx.x;
  const bool is_pair = (g < NP);

  const float *W0, *W1, *w2p, *bv0, *bv1;
  float b2s, z;
  int off0 = 0, off1 = 0, fid = 0;
  if (is_pair) {
    W0  = pw0 + (size_t)g * (2 * NE * NH);
    W1  = pw1 + (size_t)g * (NH * NH);
    w2p = pw2 + (size_t)g * NH;
    bv0 = pb0 + (size_t)g * NH;
    bv1 = pb1 + (size_t)g * NH;
    b2s = pb2[g];
    z   = smoothz(z_pairs[g]);
    off0 = foff[pairs_list[2 * g + 0]];
    off1 = foff[pairs_list[2 * g + 1]];
  } else {
    fid = g - NP;
    W0  = mw0 + (size_t)fid * (NE * NH);
    W1  = mw1 + (size_t)fid * (NH * NH);
    w2p = mw2 + (size_t)fid * NH;
    bv0 = mb0 + (size_t)fid * NH;
    bv1 = mb1 + (size_t)fid * NH;
    b2s = mb2[fid];
    z   = smoothz(z_main[fid]);
    off0 = foff[fid];
  }

  // ---- per-wave weight A-fragments straight into registers (issued first,
  //      long latency; needed only after the prologue barrier) ----
  const int hq = wave * 32 + l;
  f16x8 w0f[2][2];   // [mh][kb]; mains use kb=0 only
  f16x8 w1f[2][4];   // [mh][kb1]
#pragma unroll
  for (int mh = 0; mh < 2; ++mh) {
    const float* base0 = W0 + (size_t)(qd * 8) * NH + (hq + mh * 16);
    w0f[mh][0] = load_col_frag(base0);
    if (is_pair) w0f[mh][1] = load_col_frag(base0 + (size_t)32 * NH);
  }
#pragma unroll
  for (int mh = 0; mh < 2; ++mh)
#pragma unroll
    for (int kb = 0; kb < 4; ++kb)
      w1f[mh][kb] =
          load_col_frag(W1 + (size_t)(kb * 32 + qd * 8) * NH + (hq + mh * 16));

  // ---- stage biases / w2 into LDS ----
  if (t < 96) {
    const int which = t >> 5;                    // 0:b0 1:b1 2:w2
    const int i = (t & 31) * 4;
    const float* src = which == 0 ? bv0 : (which == 1 ? bv1 : w2p);
    *(float4*)&sBias[which * NH + i] = *(const float4*)(src + i);
  }

  // ---- preload ALL bin indices (kills pt->emb dependent chain in loop) ----
  const int row = t & 63;
  const int q   = t >> 6;
  const int myoff = is_pair ? ((q >> 1) ? off1 : off0) : off0;
  int binv[NT];
  if (is_pair) {
    const size_t pbase = (size_t)(2 * g + (q >> 1)) * Bsz + row;
#pragma unroll
    for (int i = 0; i < NT; ++i) binv[i] = pt[pbase + i * BT];
  } else {
#pragma unroll
    for (int i = 0; i < NT; ++i) binv[i] = mains[(i * BT + row) * NF + fid];
  }

  // raw f32 prefetch registers (convert to f16 only at store time)
  float4 er0, er1, er2, er3;
  auto ldemb = [&](int tl) {
    const int idx = binv[tl] + myoff;
    const float* er =
        emb + (size_t)idx * NE + (is_pair ? ((q & 1) * 16) : (q * 8));
    er0 = ((const float4*)er)[0];
    er1 = ((const float4*)er)[1];
    if (is_pair) {
      er2 = ((const float4*)er)[2];
      er3 = ((const float4*)er)[3];
    }
  };
  auto stemb = [&](int buf) {
    if (is_pair) {
      f16x8 h0, h1;
      h0[0] = (_Float16)er0.x; h0[1] = (_Float16)er0.y;
      h0[2] = (_Float16)er0.z; h0[3] = (_Float16)er0.w;
      h0[4] = (_Float16)er1.x; h0[5] = (_Float16)er1.y;
      h0[6] = (_Float16)er1.z; h0[7] = (_Float16)er1.w;
      h1[0] = (_Float16)er2.x; h1[1] = (_Float16)er2.y;
      h1[2] = (_Float16)er2.z; h1[3] = (_Float16)er2.w;
      h1[4] = (_Float16)er3.x; h1[5] = (_Float16)er3.y;
      h1[6] = (_Float16)er3.z; h1[7] = (_Float16)er3.w;
      const int blk0 = (2 * q)     ^ (row & 7);
      const int blk1 = (2 * q + 1) ^ (row & 7);
      *(f16x8*)&sA[buf][row * 64 + blk0 * 8] = h0;
      *(f16x8*)&sA[buf][row * 64 + blk1 * 8] = h1;
    } else {
      f16x8 h0;
      h0[0] = (_Float16)er0.x; h0[1] = (_Float16)er0.y;
      h0[2] = (_Float16)er0.z; h0[3] = (_Float16)er0.w;
      h0[4] = (_Float16)er1.x; h0[5] = (_Float16)er1.y;
      h0[6] = (_Float16)er1.z; h0[7] = (_Float16)er1.w;
      const int blk = q ^ (row & 7);
      *(f16x8*)&sA[buf][row * 64 + blk * 8] = h0;
    }
  };

  // ---- prologue: stage tile 0 ----
  ldemb(0);
  stemb(0);
  __syncthreads();  // S0: sA[0] + sBias visible

  const int hq4 = wave * 32 + qd * 4;   // h base for this lane's D rows

#pragma unroll
  for (int tile = 0; tile < NT; ++tile) {
    const int c = tile & 1;
    const _Float16* sAc = sA[c];
    const int bbase = tile * BT;

    // issue next tile's embedding loads (latency hides under GEMM0+GEMM1)
    if (tile + 1 < NT) ldemb(tile + 1);

    // ---- GEMM0: H1^T(slice) = W0^T * E^T ----
    f32x4 acc0[2][4];
#pragma unroll
    for (int mh = 0; mh < 2; ++mh) {
      const f32x4 b0q = *(const f32x4*)&sBias[hq4 + mh * 16];
#pragma unroll
      for (int nb = 0; nb < 4; ++nb) acc0[mh][nb] = b0q;
    }
#pragma unroll
    for (int nb = 0; nb < 4; ++nb) {
      const int b  = nb * 16 + l;
      const int rs = b & 7;
      const f16x8 e0 = *(const f16x8*)&sAc[b * 64 + ((qd ^ rs) * 8)];
      acc0[0][nb] = __builtin_amdgcn_mfma_f32_16x16x32_f16(w0f[0][0], e0,
                                                           acc0[0][nb], 0, 0, 0);
      acc0[1][nb] = __builtin_amdgcn_mfma_f32_16x16x32_f16(w0f[1][0], e0,
                                                           acc0[1][nb], 0, 0, 0);
      if (is_pair) {
        const f16x8 e1 = *(const f16x8*)&sAc[b * 64 + (((4 + qd) ^ rs) * 8)];
        acc0[0][nb] = __builtin_amdgcn_mfma_f32_16x16x32_f16(w0f[0][1], e1,
                                                             acc0[0][nb], 0, 0, 0);
        acc0[1][nb] = __builtin_amdgcn_mfma_f32_16x16x32_f16(w0f[1][1], e1,
                                                             acc0[1][nb], 0, 0, 0);
      }
    }

    // ---- relu + b64 store of 4 contiguous hidden per lane into sH ----
#pragma unroll
    for (int mh = 0; mh < 2; ++mh) {
      const int hb = hq4 + mh * 16;           // multiple of 4
#pragma unroll
      for (int nb = 0; nb < 4; ++nb) {
        const int b = nb * 16 + l;
        f16x4 h4;
#pragma unroll
        for (int r = 0; r < 4; ++r)
          h4[r] = (_Float16)fmaxf(acc0[mh][nb][r], 0.0f);
        const int blk = (hb >> 3) ^ (b & 7);
        *(f16x4*)&sH[b * NH + blk * 8 + (hb & 7)] = h4;
      }
    }
    __syncthreads();  // S2: sH complete

    // ---- GEMM1: H2^T(slice) = W1^T * H1 ----
    f32x4 acc1[2][4];
#pragma unroll
    for (int mh = 0; mh < 2; ++mh) {
      const f32x4 b1q = *(const f32x4*)&sBias[NH + hq4 + mh * 16];
#pragma unroll
      for (int nb = 0; nb < 4; ++nb) acc1[mh][nb] = b1q;
    }
#pragma unroll
    for (int kb = 0; kb < 4; ++kb) {
#pragma unroll
      for (int nb = 0; nb < 4; ++nb) {
        const int b = nb * 16 + l;
        const f16x8 hf =
            *(const f16x8*)&sH[b * NH + (((kb * 4 + qd) ^ (b & 7)) * 8)];
        acc1[0][nb] = __builtin_amdgcn_mfma_f32_16x16x32_f16(w1f[0][kb], hf,
                                                             acc1[0][nb], 0, 0, 0);
        acc1[1][nb] = __builtin_amdgcn_mfma_f32_16x16x32_f16(w1f[1][kb], hf,
                                                             acc1[1][nb], 0, 0, 0);
      }
    }

    // ---- layer 2: per-lane dot over 8 h', then 2-step qd reduce ----
    float yp[4] = {0.0f, 0.0f, 0.0f, 0.0f};
#pragma unroll
    for (int mh = 0; mh < 2; ++mh) {
      const f32x4 w2q = *(const f32x4*)&sBias[2 * NH + hq4 + mh * 16];
#pragma unroll
      for (int nb = 0; nb < 4; ++nb)
#pragma unroll
        for (int r = 0; r < 4; ++r)
          yp[nb] = fmaf(fmaxf(acc1[mh][nb][r], 0.0f), w2q[r], yp[nb]);
    }
#pragma unroll
    for (int nb = 0; nb < 4; ++nb) {
      yp[nb] += __shfl_xor(yp[nb], 16, 64);
      yp[nb] += __shfl_xor(yp[nb], 32, 64);
    }
    if (qd == 0) {
#pragma unroll
      for (int nb = 0; nb < 4; ++nb) sRed[wave * BT + nb * 16 + l] = yp[nb];
    }

    // write next tile's activations into the other sA buffer
    if (tile + 1 < NT) stemb(c ^ 1);

    __syncthreads();  // S3: sRed + sA[next] ready; sA[c]/sH fully consumed
    if (t < BT) {
      const float s =
          sRed[t] + sRed[BT + t] + sRed[2 * BT + t] + sRed[3 * BT + t];
      ws[(size_t)g * Bsz + bbase + t] = (s + b2s) * z;
    }
  }
}

__global__ void reduce1_kernel(const float* __restrict__ part,
                               float* __restrict__ s2) {
  const int b   = blockIdx.x * 256 + threadIdx.x;
  const int seg = blockIdx.y;
  float s = 0.0f;
#pragma unroll 8
  for (int g = seg * GSEG; g < (seg + 1) * GSEG; ++g)
    s += part[(size_t)g * Bsz + b];
  s2[seg * Bsz + b] = s;
}

__global__ void reduce2_kernel(const float* __restrict__ s2,
                               float* __restrict__ out) {
  const int b = blockIdx.x * 256 + threadIdx.x;
  float s = 0.0f;
#pragma unroll
  for (int k = 0; k < NSEG; ++k) s += s2[k * Bsz + b];
  out[b] = s;
}

extern "C" void kernel_launch(void* const* d_in, const int* in_sizes, int n_in,
                              void* d_out, int out_size, void* d_ws,
                              size_t ws_size, hipStream_t stream) {
  const int*   mains      = (const int*)d_in[0];
  const int*   pairs      = (const int*)d_in[1];
  const float* emb        = (const float*)d_in[2];
  const float* mw0        = (const float*)d_in[3];
  const float* mw1        = (const float*)d_in[4];
  const float* mw2        = (const float*)d_in[5];
  const float* mb0        = (const float*)d_in[6];
  const float* mb1        = (const float*)d_in[7];
  const float* mb2        = (const float*)d_in[8];
  const float* z_main     = (const float*)d_in[9];
  const float* pw0        = (const float*)d_in[10];
  const float* pw1        = (const float*)d_in[11];
  const float* pw2        = (const float*)d_in[12];
  const float* pb0        = (const float*)d_in[13];
  const float* pb1        = (const float*)d_in[14];
  const float* pb2        = (const float*)d_in[15];
  const float* z_pairs    = (const float*)d_in[16];
  const int*   pairs_list = (const int*)d_in[17];
  const int*   foff       = (const int*)d_in[18];
  float* ws   = (float*)d_ws;
  float* out  = (float*)d_out;
  float* part = ws;
  float* s2   = ws + WS_S2;
  int*   pt   = (int*)(ws + WS_PT);

  transpose_pairs_kernel<<<dim3(16, 126), 256, 0, stream>>>(pairs, pt);
  fused_groups_kernel<<<NG, 256, 0, stream>>>(
      mains, pt, emb, mw0, mw1, mw2, mb0, mb1, mb2, z_main, pw0, pw1, pw2,
      pb0, pb1, pb2, z_pairs, pairs_list, foff, part);
  reduce1_kernel<<<dim3(2, NSEG), 256, 0, stream>>>(part, s2);
  reduce2_kernel<<<2, 256, 0, stream>>>(s2, out);
}

// Round 3
// 336.472 us; speedup vs baseline: 1.1642x; 1.1642x over previous
//
#include <hip/hip_runtime.h>

// DNAMite GAM on MI355X. Round 6: round-5 latency hiding WITHOUT the spill.
// Round 5's regression was scratch traffic (WRITE_SIZE 4MB->100MB): the
// launch_bounds(256,4) register cap + double-buffer/prefetch live state
// collided and the compiler spilled. Now: launch_bounds(256,3) (proven no
// spill), SINGLE-buffered sA (legal because all GEMM0 reads of sA complete
// before the S2 barrier, so next-tile stores can land after S2), binv
// preload kills the pt->emb dependent chain, loads issued before GEMM0 with
// the vmcnt wait landing at the post-S2 store. 2 barriers/tile, LDS 27KB.

typedef _Float16 f16x8 __attribute__((ext_vector_type(8)));
typedef _Float16 f16x4 __attribute__((ext_vector_type(4)));
typedef float f32x4 __attribute__((ext_vector_type(4)));

constexpr int Bsz = 512;
constexpr int NF  = 64;
constexpr int NE  = 32;
constexpr int NH  = 128;
constexpr int NP  = 2016;
constexpr int NG  = NP + NF;       // 2080 groups = grid
constexpr int BT  = 64;            // batch tile
constexpr int NT  = Bsz / BT;      // 8 tiles
constexpr int NSEG = 8, GSEG = NG / NSEG;  // 260

// ws layout (floats): [NG*Bsz] partials | [NSEG*Bsz] stage2 | pairsT ints
constexpr size_t WS_S2 = (size_t)NG * Bsz;
constexpr size_t WS_PT = WS_S2 + (size_t)NSEG * Bsz;

__device__ __forceinline__ float smoothz(float z) {
  float s = fmaf(-2.0f * z * z, z, fmaf(1.5f, z, 0.5f));
  if (z <= -0.5f) s = 0.0f;
  if (z >=  0.5f) s = 1.0f;
  return s;
}

// [512][4032] -> [4032][512] int transpose, LDS-tiled 32x32.
__global__ void transpose_pairs_kernel(const int* __restrict__ pairs,
                                       int* __restrict__ pt) {
  __shared__ int tile[32][33];
  const int bt = blockIdx.x;
  const int qt = blockIdx.y;
  const int t  = threadIdx.x;
  const int tq = t & 7, tb = t >> 3;
  const int brow  = bt * 32 + tb;
  const int qbase = qt * 32 + tq * 4;
#pragma unroll
  for (int j = 0; j < 4; ++j)
    tile[tb][tq * 4 + j] = pairs[brow * (2 * NP) + qbase + j];
  __syncthreads();
  const int ob = t & 7, oq = t >> 3;
  const int qrow = qt * 32 + oq;
#pragma unroll
  for (int j = 0; j < 4; ++j)
    pt[(size_t)qrow * Bsz + bt * 32 + ob * 4 + j] = tile[ob * 4 + j][oq];
}

// Load one A-fragment of W^T: 8 consecutive k (rows of W) at a fixed column.
__device__ __forceinline__ f16x8 load_col_frag(const float* __restrict__ p) {
  f16x8 f;
#pragma unroll
  for (int j = 0; j < 8; ++j) f[j] = (_Float16)p[(size_t)(j * NH)];
  return f;
}

__global__ __launch_bounds__(256, 3) void fused_groups_kernel(
    const int* __restrict__ mains, const int* __restrict__ pt,
    const float* __restrict__ emb,
    const float* __restrict__ mw0, const float* __restrict__ mw1,
    const float* __restrict__ mw2, const float* __restrict__ mb0,
    const float* __restrict__ mb1, const float* __restrict__ mb2,
    const float* __restrict__ z_main,
    const float* __restrict__ pw0, const float* __restrict__ pw1,
    const float* __restrict__ pw2, const float* __restrict__ pb0,
    const float* __restrict__ pb1, const float* __restrict__ pb2,
    const float* __restrict__ z_pairs,
    const int* __restrict__ pairs_list, const int* __restrict__ foff,
    float* __restrict__ ws) {
  __shared__ _Float16 sA[BT * 64];              // [batch][embed] swizzled, 8 KB
  __shared__ _Float16 sH[BT * NH];              // [batch][hidden] swizzled, 16 KB
  __shared__ __align__(16) float sBias[3 * NH]; // b0 | b1 | w2
  __shared__ float sRed[4 * BT];

  const int t    = threadIdx.x;
  const int wave = t >> 6;
  const int lane = t & 63;
  const int l    = lane & 15;
  const int qd   = lane >> 4;
  const int g    = blockIdx.x;
  const bool is_pair = (g < NP);

  const float *W0, *W1, *w2p, *bv0, *bv1;
  float b2s, z;
  int off0 = 0, off1 = 0, fid = 0;
  if (is_pair) {
    W0  = pw0 + (size_t)g * (2 * NE * NH);
    W1  = pw1 + (size_t)g * (NH * NH);
    w2p = pw2 + (size_t)g * NH;
    bv0 = pb0 + (size_t)g * NH;
    bv1 = pb1 + (size_t)g * NH;
    b2s = pb2[g];
    z   = smoothz(z_pairs[g]);
    off0 = foff[pairs_list[2 * g + 0]];
    off1 = foff[pairs_list[2 * g + 1]];
  } else {
    fid = g - NP;
    W0  = mw0 + (size_t)fid * (NE * NH);
    W1  = mw1 + (size_t)fid * (NH * NH);
    w2p = mw2 + (size_t)fid * NH;
    bv0 = mb0 + (size_t)fid * NH;
    bv1 = mb1 + (size_t)fid * NH;
    b2s = mb2[fid];
    z   = smoothz(z_main[fid]);
    off0 = foff[fid];
  }

  // ---- per-wave weight A-fragments straight into registers ----
  const int hq = wave * 32 + l;
  f16x8 w0f[2][2];   // [mh][kb]; mains use kb=0 only
  f16x8 w1f[2][4];   // [mh][kb1]
#pragma unroll
  for (int mh = 0; mh < 2; ++mh) {
    const float* base0 = W0 + (size_t)(qd * 8) * NH + (hq + mh * 16);
    w0f[mh][0] = load_col_frag(base0);
    if (is_pair) w0f[mh][1] = load_col_frag(base0 + (size_t)32 * NH);
  }
#pragma unroll
  for (int mh = 0; mh < 2; ++mh)
#pragma unroll
    for (int kb = 0; kb < 4; ++kb)
      w1f[mh][kb] =
          load_col_frag(W1 + (size_t)(kb * 32 + qd * 8) * NH + (hq + mh * 16));

  // ---- stage biases / w2 into LDS ----
  if (t < 96) {
    const int which = t >> 5;                    // 0:b0 1:b1 2:w2
    const int i = (t & 31) * 4;
    const float* src = which == 0 ? bv0 : (which == 1 ? bv1 : w2p);
    *(float4*)&sBias[which * NH + i] = *(const float4*)(src + i);
  }

  // ---- preload ALL bin indices (kills pt->emb dependent chain in loop) ----
  const int row = t & 63;
  const int q   = t >> 6;
  const int myoff = is_pair ? ((q >> 1) ? off1 : off0) : off0;
  int binv[NT];   // only ever indexed with compile-time constants (unrolled)
  if (is_pair) {
    const size_t pbase = (size_t)(2 * g + (q >> 1)) * Bsz + row;
#pragma unroll
    for (int i = 0; i < NT; ++i) binv[i] = pt[pbase + i * BT];
  } else {
#pragma unroll
    for (int i = 0; i < NT; ++i) binv[i] = mains[(i * BT + row) * NF + fid];
  }

  // raw f32 prefetch registers (convert to f16 only at store time so the
  // vmcnt wait lands at the post-S2 store, not before GEMM0)
  float4 er0, er1, er2, er3;
  auto ldemb = [&](int bin) {
    const int idx = bin + myoff;
    const float* er =
        emb + (size_t)idx * NE + (is_pair ? ((q & 1) * 16) : (q * 8));
    er0 = ((const float4*)er)[0];
    er1 = ((const float4*)er)[1];
    if (is_pair) {
      er2 = ((const float4*)er)[2];
      er3 = ((const float4*)er)[3];
    }
  };
  auto stemb = [&]() {
    if (is_pair) {
      f16x8 h0, h1;
      h0[0] = (_Float16)er0.x; h0[1] = (_Float16)er0.y;
      h0[2] = (_Float16)er0.z; h0[3] = (_Float16)er0.w;
      h0[4] = (_Float16)er1.x; h0[5] = (_Float16)er1.y;
      h0[6] = (_Float16)er1.z; h0[7] = (_Float16)er1.w;
      h1[0] = (_Float16)er2.x; h1[1] = (_Float16)er2.y;
      h1[2] = (_Float16)er2.z; h1[3] = (_Float16)er2.w;
      h1[4] = (_Float16)er3.x; h1[5] = (_Float16)er3.y;
      h1[6] = (_Float16)er3.z; h1[7] = (_Float16)er3.w;
      const int blk0 = (2 * q)     ^ (row & 7);
      const int blk1 = (2 * q + 1) ^ (row & 7);
      *(f16x8*)&sA[row * 64 + blk0 * 8] = h0;
      *(f16x8*)&sA[row * 64 + blk1 * 8] = h1;
    } else {
      f16x8 h0;
      h0[0] = (_Float16)er0.x; h0[1] = (_Float16)er0.y;
      h0[2] = (_Float16)er0.z; h0[3] = (_Float16)er0.w;
      h0[4] = (_Float16)er1.x; h0[5] = (_Float16)er1.y;
      h0[6] = (_Float16)er1.z; h0[7] = (_Float16)er1.w;
      const int blk = q ^ (row & 7);
      *(f16x8*)&sA[row * 64 + blk * 8] = h0;
    }
  };

  // ---- prologue: stage tile 0 ----
  ldemb(binv[0]);
  stemb();
  __syncthreads();  // S0: sA(tile0) + sBias visible

  const int hq4 = wave * 32 + qd * 4;   // h base for this lane's D rows

#pragma unroll
  for (int tile = 0; tile < NT; ++tile) {
    const int bbase = tile * BT;

    // issue next tile's embedding loads (latency hides under GEMM0 + sH)
    if (tile + 1 < NT) ldemb(binv[tile + 1]);

    // ---- GEMM0: H1^T(slice) = W0^T * E^T ----
    f32x4 acc0[2][4];
#pragma unroll
    for (int mh = 0; mh < 2; ++mh) {
      const f32x4 b0q = *(const f32x4*)&sBias[hq4 + mh * 16];
#pragma unroll
      for (int nb = 0; nb < 4; ++nb) acc0[mh][nb] = b0q;
    }
#pragma unroll
    for (int nb = 0; nb < 4; ++nb) {
      const int b  = nb * 16 + l;
      const int rs = b & 7;
      const f16x8 e0 = *(const f16x8*)&sA[b * 64 + ((qd ^ rs) * 8)];
      acc0[0][nb] = __builtin_amdgcn_mfma_f32_16x16x32_f16(w0f[0][0], e0,
                                                           acc0[0][nb], 0, 0, 0);
      acc0[1][nb] = __builtin_amdgcn_mfma_f32_16x16x32_f16(w0f[1][0], e0,
                                                           acc0[1][nb], 0, 0, 0);
      if (is_pair) {
        const f16x8 e1 = *(const f16x8*)&sA[b * 64 + (((4 + qd) ^ rs) * 8)];
        acc0[0][nb] = __builtin_amdgcn_mfma_f32_16x16x32_f16(w0f[0][1], e1,
                                                             acc0[0][nb], 0, 0, 0);
        acc0[1][nb] = __builtin_amdgcn_mfma_f32_16x16x32_f16(w0f[1][1], e1,
                                                             acc0[1][nb], 0, 0, 0);
      }
    }

    // ---- relu + b64 store of 4 contiguous hidden per lane into sH ----
#pragma unroll
    for (int mh = 0; mh < 2; ++mh) {
      const int hb = hq4 + mh * 16;           // multiple of 4
#pragma unroll
      for (int nb = 0; nb < 4; ++nb) {
        const int b = nb * 16 + l;
        f16x4 h4;
#pragma unroll
        for (int r = 0; r < 4; ++r)
          h4[r] = (_Float16)fmaxf(acc0[mh][nb][r], 0.0f);
        const int blk = (hb >> 3) ^ (b & 7);
        *(f16x4*)&sH[b * NH + blk * 8 + (hb & 7)] = h4;
      }
    }
    __syncthreads();  // S2: sH complete; ALL waves done reading sA

    // write next tile's activations into sA (safe: GEMM0 reads all done)
    if (tile + 1 < NT) stemb();

    // ---- GEMM1: H2^T(slice) = W1^T * H1 ----
    f32x4 acc1[2][4];
#pragma unroll
    for (int mh = 0; mh < 2; ++mh) {
      const f32x4 b1q = *(const f32x4*)&sBias[NH + hq4 + mh * 16];
#pragma unroll
      for (int nb = 0; nb < 4; ++nb) acc1[mh][nb] = b1q;
    }
#pragma unroll
    for (int kb = 0; kb < 4; ++kb) {
#pragma unroll
      for (int nb = 0; nb < 4; ++nb) {
        const int b = nb * 16 + l;
        const f16x8 hf =
            *(const f16x8*)&sH[b * NH + (((kb * 4 + qd) ^ (b & 7)) * 8)];
        acc1[0][nb] = __builtin_amdgcn_mfma_f32_16x16x32_f16(w1f[0][kb], hf,
                                                             acc1[0][nb], 0, 0, 0);
        acc1[1][nb] = __builtin_amdgcn_mfma_f32_16x16x32_f16(w1f[1][kb], hf,
                                                             acc1[1][nb], 0, 0, 0);
      }
    }

    // ---- layer 2: per-lane dot over 8 h', then 2-step qd reduce ----
    float yp[4] = {0.0f, 0.0f, 0.0f, 0.0f};
#pragma unroll
    for (int mh = 0; mh < 2; ++mh) {
      const f32x4 w2q = *(const f32x4*)&sBias[2 * NH + hq4 + mh * 16];
#pragma unroll
      for (int nb = 0; nb < 4; ++nb)
#pragma unroll
        for (int r = 0; r < 4; ++r)
          yp[nb] = fmaf(fmaxf(acc1[mh][nb][r], 0.0f), w2q[r], yp[nb]);
    }
#pragma unroll
    for (int nb = 0; nb < 4; ++nb) {
      yp[nb] += __shfl_xor(yp[nb], 16, 64);
      yp[nb] += __shfl_xor(yp[nb], 32, 64);
    }
    if (qd == 0) {
#pragma unroll
      for (int nb = 0; nb < 4; ++nb) sRed[wave * BT + nb * 16 + l] = yp[nb];
    }

    __syncthreads();  // S3: sRed + sA(next tile) ready; sH fully consumed
    if (t < BT) {
      const float s =
          sRed[t] + sRed[BT + t] + sRed[2 * BT + t] + sRed[3 * BT + t];
      ws[(size_t)g * Bsz + bbase + t] = (s + b2s) * z;
    }
  }
}

__global__ void reduce1_kernel(const float* __restrict__ part,
                               float* __restrict__ s2) {
  const int b   = blockIdx.x * 256 + threadIdx.x;
  const int seg = blockIdx.y;
  float s = 0.0f;
#pragma unroll 8
  for (int g = seg * GSEG; g < (seg + 1) * GSEG; ++g)
    s += part[(size_t)g * Bsz + b];
  s2[seg * Bsz + b] = s;
}

__global__ void reduce2_kernel(const float* __restrict__ s2,
                               float* __restrict__ out) {
  const int b = blockIdx.x * 256 + threadIdx.x;
  float s = 0.0f;
#pragma unroll
  for (int k = 0; k < NSEG; ++k) s += s2[k * Bsz + b];
  out[b] = s;
}

extern "C" void kernel_launch(void* const* d_in, const int* in_sizes, int n_in,
                              void* d_out, int out_size, void* d_ws,
                              size_t ws_size, hipStream_t stream) {
  const int*   mains      = (const int*)d_in[0];
  const int*   pairs      = (const int*)d_in[1];
  const float* emb        = (const float*)d_in[2];
  const float* mw0        = (const float*)d_in[3];
  const float* mw1        = (const float*)d_in[4];
  const float* mw2        = (const float*)d_in[5];
  const float* mb0        = (const float*)d_in[6];
  const float* mb1        = (const float*)d_in[7];
  const float* mb2        = (const float*)d_in[8];
  const float* z_main     = (const float*)d_in[9];
  const float* pw0        = (const float*)d_in[10];
  const float* pw1        = (const float*)d_in[11];
  const float* pw2        = (const float*)d_in[12];
  const float* pb0        = (const float*)d_in[13];
  const float* pb1        = (const float*)d_in[14];
  const float* pb2        = (const float*)d_in[15];
  const float* z_pairs    = (const float*)d_in[16];
  const int*   pairs_list = (const int*)d_in[17];
  const int*   foff       = (const int*)d_in[18];
  float* ws   = (float*)d_ws;
  float* out  = (float*)d_out;
  float* part = ws;
  float* s2   = ws + WS_S2;
  int*   pt   = (int*)(ws + WS_PT);

  transpose_pairs_kernel<<<dim3(16, 126), 256, 0, stream>>>(pairs, pt);
  fused_groups_kernel<<<NG, 256, 0, stream>>>(
      mains, pt, emb, mw0, mw1, mw2, mb0, mb1, mb2, z_main, pw0, pw1, pw2,
      pb0, pb1, pb2, z_pairs, pairs_list, foff, part);
  reduce1_kernel<<<dim3(2, NSEG), 256, 0, stream>>>(part, s2);
  reduce2_kernel<<<2, 256, 0, stream>>>(s2, out);
}